// Round 1
// 287.853 us; speedup vs baseline: 1.0376x; 1.0376x over previous
//
#include <hip/hip_runtime.h>
#include <hip/hip_bf16.h>

// GraphTransformerLayer: B=8, N=1024, E=256, H=8, D=32, C=4 (all fp32 in/out)
#define BATCH 8
#define SEQ   1024
#define EMB   256
#define NH    8
#define HD    32
#define QSCALE 0.2550030053f   // log2(e)/sqrt(32), folded into Wq/bq

typedef __attribute__((ext_vector_type(8))) short short8;
typedef __attribute__((ext_vector_type(4))) float floatx4;

__device__ __forceinline__ ushort f2bf(float f) {
    __hip_bfloat16 h = __float2bfloat16(f);
    return *reinterpret_cast<ushort*>(&h);
}

// async 16B/lane global->LDS DMA: each lane loads 16B from its own global
// address into wave-uniform LDS base + lane*16 (m97/m104 semantics).
__device__ __forceinline__ void gload_lds16(const float4* g, float4* l) {
    __builtin_amdgcn_global_load_lds(
        (const __attribute__((address_space(1))) unsigned int*)g,
        (__attribute__((address_space(3))) unsigned int*)l, 16, 0, 0);
}

// ---------------------------------------------------------------------------
// Kernel 0: prep — transpose Wq,Wk,Wv,Wo (fp32 [K][N]) to bf16 [N][K].
// Wq pre-scaled by log2(e)/sqrt(32). 256 blocks: matrix = blk/64, 8x8 tiles.
// ---------------------------------------------------------------------------
__global__ __launch_bounds__(256) void prep_kernel(
    const float* __restrict__ Wq, const float* __restrict__ Wk,
    const float* __restrict__ Wv, const float* __restrict__ Wo,
    ushort* __restrict__ Wqt, ushort* __restrict__ Wkt,
    ushort* __restrict__ Wvt, ushort* __restrict__ Wot)
{
    __shared__ float tilebuf[32][33];
    const int blk = blockIdx.x;
    const int mat = blk >> 6, tile = blk & 63;
    const int ti = tile >> 3, tj = tile & 7;     // ti: k-tile, tj: n-tile
    const float* W = (mat == 0) ? Wq : (mat == 1) ? Wk : (mat == 2) ? Wv : Wo;
    ushort* Wt = (mat == 0) ? Wqt : (mat == 1) ? Wkt : (mat == 2) ? Wvt : Wot;
    const float scale = (mat == 0) ? QSCALE : 1.0f;

    const int tx = threadIdx.x & 31, ty = threadIdx.x >> 5;  // 32 x 8
    #pragma unroll
    for (int p = 0; p < 4; ++p)
        tilebuf[ty + p * 8][tx] = W[(size_t)(ti * 32 + ty + p * 8) * EMB + tj * 32 + tx];
    __syncthreads();
    #pragma unroll
    for (int p = 0; p < 4; ++p)
        Wt[(size_t)(tj * 32 + ty + p * 8) * EMB + ti * 32 + tx] =
            f2bf(tilebuf[tx][ty + p * 8] * scale);
}

// ---------------------------------------------------------------------------
// Kernel 1: QKV projection as MFMA GEMM.
// Q,K -> [B,H,N,D] bf16.  V -> [B,H,D,Nperm] bf16 where within every 32-key
// chunk keys are stored in quad-interleaved slot order
//   slot(8q+i) holds key  4q+i      (i<4)
//                    key  16+4q+i-4 (i>=4)
// so that attn's PV A-frag (V) k-slots line up with the swapped-QK^T
// accumulator layout (P^T) used directly as the PV B-frag.
// ---------------------------------------------------------------------------
__global__ __launch_bounds__(256) void qkv_gemm(
    const float* __restrict__ x,
    const ushort* __restrict__ Wqt, const ushort* __restrict__ Wkt,
    const ushort* __restrict__ Wvt,
    const float* __restrict__ bq, const float* __restrict__ bk,
    const float* __restrict__ bv,
    ushort* __restrict__ Qb, ushort* __restrict__ Kb, ushort* __restrict__ Vt)
{
    const int mat = blockIdx.y;
    const ushort* __restrict__ Wt = (mat == 0) ? Wqt : (mat == 1) ? Wkt : Wvt;
    const float* __restrict__ bias = (mat == 0) ? bq : (mat == 1) ? bk : bv;
    const float bscale = (mat == 0) ? QSCALE : 1.0f;

    const int w = threadIdx.x >> 6, lane = threadIdx.x & 63;
    const int quad = lane >> 4, l16 = lane & 15;
    const int row0 = blockIdx.x * 64 + w * 16;

    floatx4 acc[16];
    #pragma unroll
    for (int i = 0; i < 16; ++i) acc[i] = (floatx4){0.f, 0.f, 0.f, 0.f};

    const float* __restrict__ xrow = x + (size_t)(row0 + l16) * EMB + quad * 8;

    #pragma unroll
    for (int ks = 0; ks < 8; ++ks) {
        const float4 xa0 = *(const float4*)(xrow + ks * 32);
        const float4 xa1 = *(const float4*)(xrow + ks * 32 + 4);
        ushort au[8] = {f2bf(xa0.x), f2bf(xa0.y), f2bf(xa0.z), f2bf(xa0.w),
                        f2bf(xa1.x), f2bf(xa1.y), f2bf(xa1.z), f2bf(xa1.w)};
        const short8 a = *(const short8*)au;
        #pragma unroll
        for (int i = 0; i < 16; ++i) {
            const short8 bf = *(const short8*)(Wt + (size_t)(i * 16 + l16) * EMB + ks * 32 + quad * 8);
            acc[i] = __builtin_amdgcn_mfma_f32_16x16x32_bf16(a, bf, acc[i], 0, 0, 0);
        }
    }

    const int gr0 = row0 + quad * 4;
    if (mat < 2) {
        ushort* __restrict__ dst = (mat == 0) ? Qb : Kb;
        #pragma unroll
        for (int i = 0; i < 16; ++i) {
            const int c = i * 16 + l16, h = c >> 5, d = c & (HD - 1);
            const float bb = bias[c] * bscale;
            #pragma unroll
            for (int r = 0; r < 4; ++r) {
                const int gr = gr0 + r, b = gr >> 10, n = gr & (SEQ - 1);
                dst[((size_t)(b * NH + h) * SEQ + n) * HD + d] = f2bf(acc[i][r] + bb);
            }
        }
    } else {
        const int b = gr0 >> 10, n0 = gr0 & (SEQ - 1);
        const int j0 = n0 & 31;
        const int slot = (j0 < 16) ? ((j0 >> 2) << 3)
                                   : ((((j0 - 16) >> 2) << 3) + 4);
        const int nperm = (n0 & ~31) | slot;
        #pragma unroll
        for (int i = 0; i < 16; ++i) {
            const int c = i * 16 + l16, h = c >> 5, d = c & (HD - 1);
            const float bb = bias[c];
            ushort4 t4;
            t4.x = f2bf(acc[i][0] + bb); t4.y = f2bf(acc[i][1] + bb);
            t4.z = f2bf(acc[i][2] + bb); t4.w = f2bf(acc[i][3] + bb);
            *(ushort4*)(Vt + ((size_t)(b * NH + h) * HD + d) * SEQ + nperm) = t4;
        }
    }
}

// ---------------------------------------------------------------------------
// Kernel 2: attention, swapped-QK^T form.
//   s = mfma(K, Q)  -> acc holds P^T: lane (quad,l16) = S[key0+16b+4q+r][q0+l16]
// Bias+exp2 on the VALU as before (adj stays fp32 -> numerics unchanged), but
// P^T is packed to bf16 IN REGISTERS and fed straight to PV as the B-frag:
//   o = mfma(Vperm_frag, P^T_frag, o)   -> o[r] = ctx[d=4q+r(+16)][q=l16]
// This deletes the P LDS round-trip entirely (no 72B-stride misaligned b128
// reads, no 4.2M bank-conflict cycles, no lgkmcnt(0) stall) and shrinks LDS
// to the adj tile only: 33280 B -> 4 blocks/CU.
// adj tile double-buffered via global_load_lds DMA exactly as before.
// ---------------------------------------------------------------------------
__global__ __launch_bounds__(512) void attn_kernel(
    const ushort* __restrict__ Qb, const ushort* __restrict__ Kb,
    const ushort* __restrict__ Vt, const float* __restrict__ adj,
    const float* __restrict__ Wa, const float* __restrict__ ba,
    float* __restrict__ cp, float* __restrict__ lsum)
{
    __shared__ float4 Atile[2][16][65];      // +1 float4 row pad (DMA fills [0,64))
    const int tid = threadIdx.x, h = tid >> 6, lane = tid & 63;
    const int quad = lane >> 4, l16 = lane & 15;
    const int q0 = blockIdx.x * 16, b = blockIdx.y, z = blockIdx.z;
    const int bh = b * NH + h;
    const int kz = z * 512;

    const float LOG2E = 1.4426950408889634f;
    const float wa0 = Wa[0 * NH + h] * LOG2E, wa1 = Wa[1 * NH + h] * LOG2E;
    const float wa2 = Wa[2 * NH + h] * LOG2E, wa3 = Wa[3 * NH + h] * LOG2E;
    const float bah = ba[h] * LOG2E;

    // Q frag (B-operand of swapped QK): rows = q0+l16, k = d
    const short8 aq = *(const short8*)(Qb + ((size_t)bh * SEQ + q0 + l16) * HD + quad * 8);

    floatx4 o0 = {0.f, 0.f, 0.f, 0.f}, o1 = {0.f, 0.f, 0.f, 0.f};
    float lacc = 0.f;

    const float4* __restrict__ adjb = (const float4*)adj + (size_t)b * SEQ * SEQ;
    // wave h DMAs adj rows 2h and 2h+1 of the block's 16-row tile
    const float4* __restrict__ asrc0 = adjb + (size_t)(q0 + 2 * h)     * SEQ + kz + lane;
    const float4* __restrict__ asrc1 = adjb + (size_t)(q0 + 2 * h + 1) * SEQ + kz + lane;

    const ushort* __restrict__ Kbase = Kb + (size_t)bh * SEQ * HD + (size_t)l16 * HD + quad * 8;
    const ushort* __restrict__ Vb0 = Vt + ((size_t)bh * HD + l16) * SEQ + quad * 8;
    const ushort* __restrict__ Vb1 = Vt + ((size_t)bh * HD + 16 + l16) * SEQ + quad * 8;

    // prologue: DMA tile 0
    gload_lds16(asrc0, &Atile[0][2 * h][0]);
    gload_lds16(asrc1, &Atile[0][2 * h + 1][0]);
    __syncthreads();   // implicit vmcnt(0) drain -> tile 0 resident

    for (int it = 0; it < 8; ++it) {          // 8 x 64 = 512 keys per split
        const int cur = it & 1;
        const int key0 = kz + it * 64;

        if (it < 7) {                          // async prefetch of next tile
            gload_lds16(asrc0 + (it + 1) * 64, &Atile[cur ^ 1][2 * h][0]);
            gload_lds16(asrc1 + (it + 1) * 64, &Atile[cur ^ 1][2 * h + 1][0]);
        }

        // K frags (A-operand): rows = keys, k = d
        const short8 k0 = *(const short8*)(Kbase + (size_t)(key0)      * HD);
        const short8 k1 = *(const short8*)(Kbase + (size_t)(key0 + 16) * HD);
        const short8 k2 = *(const short8*)(Kbase + (size_t)(key0 + 32) * HD);
        const short8 k3 = *(const short8*)(Kbase + (size_t)(key0 + 48) * HD);
        const floatx4 zz = {0.f, 0.f, 0.f, 0.f};
        floatx4 s0 = __builtin_amdgcn_mfma_f32_16x16x32_bf16(k0, aq, zz, 0, 0, 0);
        floatx4 s1 = __builtin_amdgcn_mfma_f32_16x16x32_bf16(k1, aq, zz, 0, 0, 0);
        floatx4 s2 = __builtin_amdgcn_mfma_f32_16x16x32_bf16(k2, aq, zz, 0, 0, 0);
        floatx4 s3 = __builtin_amdgcn_mfma_f32_16x16x32_bf16(k3, aq, zz, 0, 0, 0);

        // bias + exp2; lane covers q = l16, keys = 16b + 4*quad + r
        // Atile read pattern is bank-balanced: residue (l16+4q+r)%8 covers all
        // 8 float4 groups 8x each -> conflict-free.
        ushort pu0[8], pu1[8];
        #pragma unroll
        for (int r = 0; r < 4; ++r) {
            const int col = 4 * quad + r;
            const float4 a0 = Atile[cur][l16][col];
            const float4 a1 = Atile[cur][l16][16 + col];
            const float4 a2 = Atile[cur][l16][32 + col];
            const float4 a3 = Atile[cur][l16][48 + col];
            const float b0 = fmaf(a0.x, wa0, fmaf(a0.y, wa1, fmaf(a0.z, wa2, fmaf(a0.w, wa3, bah))));
            const float b1 = fmaf(a1.x, wa0, fmaf(a1.y, wa1, fmaf(a1.z, wa2, fmaf(a1.w, wa3, bah))));
            const float b2 = fmaf(a2.x, wa0, fmaf(a2.y, wa1, fmaf(a2.z, wa2, fmaf(a2.w, wa3, bah))));
            const float b3 = fmaf(a3.x, wa0, fmaf(a3.y, wa1, fmaf(a3.z, wa2, fmaf(a3.w, wa3, bah))));
            const float p0 = exp2f(s0[r] + b0);
            const float p1 = exp2f(s1[r] + b1);
            const float p2 = exp2f(s2[r] + b2);
            const float p3 = exp2f(s3[r] + b3);
            lacc += (p0 + p1) + (p2 + p3);
            pu0[r]     = f2bf(p0);   // k-slot 8*quad+r     -> key 16*0+4q+r
            pu0[4 + r] = f2bf(p1);   // k-slot 8*quad+4+r   -> key 16*1+4q+r
            pu1[r]     = f2bf(p2);   // same, keys +32
            pu1[4 + r] = f2bf(p3);   // same, keys +48
        }
        const short8 pf0 = *(const short8*)pu0;
        const short8 pf1 = *(const short8*)pu1;

        // V frags (A-operand, quad-interleaved key slots match pf k-slots)
        const short8 v00 = *(const short8*)(Vb0 + key0);        // d=l16,    keys 0-31
        const short8 v10 = *(const short8*)(Vb1 + key0);        // d=16+l16, keys 0-31
        const short8 v01 = *(const short8*)(Vb0 + key0 + 32);   // d=l16,    keys 32-63
        const short8 v11 = *(const short8*)(Vb1 + key0 + 32);   // d=16+l16, keys 32-63
        o0 = __builtin_amdgcn_mfma_f32_16x16x32_bf16(v00, pf0, o0, 0, 0, 0);
        o1 = __builtin_amdgcn_mfma_f32_16x16x32_bf16(v10, pf0, o1, 0, 0, 0);
        o0 = __builtin_amdgcn_mfma_f32_16x16x32_bf16(v01, pf1, o0, 0, 0, 0);
        o1 = __builtin_amdgcn_mfma_f32_16x16x32_bf16(v11, pf1, o1, 0, 0, 0);

        __syncthreads();   // all waves done with Atile[cur]; next DMA arrived
    }

    // key dim is lane-local now; only the quad (key-block) reduction remains
    lacc += __shfl_xor(lacc, 16, 64);
    lacc += __shfl_xor(lacc, 32, 64);

    float* __restrict__ cpz = cp + (size_t)z * BATCH * SEQ * EMB;
    float* __restrict__ lsz = lsum + (size_t)z * BATCH * SEQ * NH;
    const size_t grow = (size_t)b * SEQ + q0 + l16;
    // lane holds ctx[d = 4*quad + r (+16)][q = l16] -> two coalesced 16B stores
    *(floatx4*)(cpz + grow * EMB + h * HD + 4 * quad)      = o0;
    *(floatx4*)(cpz + grow * EMB + h * HD + 16 + 4 * quad) = o1;
    if (quad == 0) lsz[grow * NH + h] = lacc;
}

// ---------------------------------------------------------------------------
// Kernel 3: outproj as MFMA GEMM. Combines the two key-split partials,
// normalizes by l, builds bf16 A-frags inline, B-frags from transposed Wo.
// Epilogue: + bo + x residual.
// Column-split over blockIdx.y: 128x2 = 256 blocks so ALL 256 CUs are active
// (was 128 blocks = half the GPU idle). Each wave: 16 rows x 128 cols.
// ---------------------------------------------------------------------------
__global__ __launch_bounds__(256) void outproj_gemm(
    const float* __restrict__ cp, const float* __restrict__ lsum,
    const ushort* __restrict__ Wot, const float* __restrict__ bo,
    const float* __restrict__ x, float* __restrict__ out)
{
    const int w = threadIdx.x >> 6, lane = threadIdx.x & 63;
    const int quad = lane >> 4, l16 = lane & 15;
    const int row0 = blockIdx.x * 64 + w * 16;
    const int c0 = blockIdx.y * 128;     // column half
    const int arow = row0 + l16;
    const float* __restrict__ cp1 = cp + (size_t)BATCH * SEQ * EMB;
    const float* __restrict__ l1  = lsum + (size_t)BATCH * SEQ * NH;

    floatx4 acc[8];
    #pragma unroll
    for (int i = 0; i < 8; ++i) acc[i] = (floatx4){0.f, 0.f, 0.f, 0.f};

    #pragma unroll
    for (int ks = 0; ks < 8; ++ks) {
        const float invl = 1.0f / (lsum[(size_t)arow * NH + ks] + l1[(size_t)arow * NH + ks]);
        const size_t cb = (size_t)arow * EMB + ks * 32 + quad * 8;
        const float4 c00 = *(const float4*)(cp + cb);
        const float4 c01 = *(const float4*)(cp + cb + 4);
        const float4 c10 = *(const float4*)(cp1 + cb);
        const float4 c11 = *(const float4*)(cp1 + cb + 4);
        ushort au[8] = {
            f2bf((c00.x + c10.x) * invl), f2bf((c00.y + c10.y) * invl),
            f2bf((c00.z + c10.z) * invl), f2bf((c00.w + c10.w) * invl),
            f2bf((c01.x + c11.x) * invl), f2bf((c01.y + c11.y) * invl),
            f2bf((c01.z + c11.z) * invl), f2bf((c01.w + c11.w) * invl)};
        const short8 a = *(const short8*)au;
        #pragma unroll
        for (int i = 0; i < 8; ++i) {
            const short8 bfr = *(const short8*)(Wot + (size_t)(c0 + i * 16 + l16) * EMB + ks * 32 + quad * 8);
            acc[i] = __builtin_amdgcn_mfma_f32_16x16x32_bf16(a, bfr, acc[i], 0, 0, 0);
        }
    }

    const int gr0 = row0 + quad * 4;
    #pragma unroll
    for (int i = 0; i < 8; ++i) {
        const int c = c0 + i * 16 + l16;
        const float bov = bo[c];
        #pragma unroll
        for (int r = 0; r < 4; ++r) {
            const size_t idx = (size_t)(gr0 + r) * EMB + c;
            out[idx] = acc[i][r] + bov + x[idx];
        }
    }
}

extern "C" void kernel_launch(void* const* d_in, const int* in_sizes, int n_in,
                              void* d_out, int out_size, void* d_ws, size_t ws_size,
                              hipStream_t stream) {
    const float* x   = (const float*)d_in[0];
    const float* adj = (const float*)d_in[1];
    const float* Wq  = (const float*)d_in[2];
    const float* bq  = (const float*)d_in[3];
    const float* Wk  = (const float*)d_in[4];
    const float* bk  = (const float*)d_in[5];
    const float* Wv  = (const float*)d_in[6];
    const float* bv  = (const float*)d_in[7];
    const float* Wo  = (const float*)d_in[8];
    const float* bo  = (const float*)d_in[9];
    const float* Wa  = (const float*)d_in[10];
    const float* ba  = (const float*)d_in[11];

    const size_t per = (size_t)BATCH * NH * SEQ * HD;   // 2,097,152
    ushort* Qb  = (ushort*)d_ws;
    ushort* Kb  = Qb + per;
    ushort* Vt  = Kb + per;
    ushort* Wqt = Vt + per;
    ushort* Wkt = Wqt + EMB * EMB;
    ushort* Wvt = Wkt + EMB * EMB;
    ushort* Wot = Wvt + EMB * EMB;
    float*  cp  = (float*)(Wot + EMB * EMB);            // 2 x 8 MB fp32
    float*  ls  = cp + 2 * (size_t)BATCH * SEQ * EMB;   // 2 x 256 KB

    prep_kernel<<<256, 256, 0, stream>>>(Wq, Wk, Wv, Wo, Wqt, Wkt, Wvt, Wot);
    qkv_gemm<<<dim3(BATCH * SEQ / 64, 3), 256, 0, stream>>>(
        x, Wqt, Wkt, Wvt, bq, bk, bv, Qb, Kb, Vt);
    attn_kernel<<<dim3(SEQ / 16, BATCH, 2), 512, 0, stream>>>(
        Qb, Kb, Vt, adj, Wa, ba, cp, ls);
    outproj_gemm<<<dim3(BATCH * SEQ / 64, 2), 256, 0, stream>>>(
        cp, ls, Wot, bo, x, (float*)d_out);
}